// Round 9
// baseline (184.935 us; speedup 1.0000x reference)
//
#include <hip/hip_runtime.h>
#include <hip/hip_fp8.h>
#include <math.h>

#define N_NODES 50000
#define N_EDGES 800000
#define NP 4                      // node partitions (12500 nodes each)
#define NS 64                     // edge segments (12500 edges each)
#define PSZ (N_NODES / NP)        // 12500
#define SSZ (N_EDGES / NS)        // 12500
#define NB 196                    // ceil(N/256)

typedef _Float16 half8 __attribute__((ext_vector_type(8)));
typedef float floatx4 __attribute__((ext_vector_type(4)));

// ---------------- fp8 e4m3 (OCP) helpers — HW cvt on gfx950 ----------------
__device__ __forceinline__ unsigned char f_to_fp8(float f) {
    __hip_fp8_e4m3 q(f);
    return (unsigned char)q.__x;
}
__device__ __forceinline__ float fp8_to_f(unsigned char u) {
    __hip_fp8_e4m3 q;
    q.__x = (__hip_fp8_storage_t)u;
    return (float)q;
}

// ---------------------------------------------------------------------------
// Fused: partitioned LDS histogram (blocks 0..NP*NS-1) + WT transpose +
// gacc/gcnt zeroing. Packed u32 counters (in low16 / out high16); the
// atomicAdd return's low bits are the edge's within-segment rank (u8).
// ---------------------------------------------------------------------------
__global__ __launch_bounds__(256) void hist_wt_kernel(const int* __restrict__ src,
                                                      const int* __restrict__ dst,
                                                      unsigned char* __restrict__ inpart,
                                                      unsigned char* __restrict__ outpart,
                                                      unsigned char* __restrict__ rank,
                                                      const float* __restrict__ W2,
                                                      const float* __restrict__ W3,
                                                      const float* __restrict__ W4,
                                                      _Float16* __restrict__ WT,
                                                      float* __restrict__ gacc) {
    __shared__ int h[PSZ + 4];                   // 12504 ints = 50016 B
    if (blockIdx.x >= NP * NS) {
        int wb = blockIdx.x - NP * NS;
        if (wb < 48) {                           // WT transpose: f32 [k][n] -> f16 [n][k]
            int i = wb * 256 + threadIdx.x;
            if (i < 3 * 4096) {
                int l = i >> 12;
                int r = i & 4095;
                int k = r >> 6, n = r & 63;
                const float* W = (l == 0) ? W2 : (l == 1) ? W3 : W4;
                WT[l * 4096 + n * 64 + k] = (_Float16)W[r];
            }
        } else {                                 // zero gacc[4096] + gcnt[64]
            for (int i = threadIdx.x; i < 64 * 64 + 64; i += 256) gacc[i] = 0.0f;
        }
        return;
    }
    int p = blockIdx.x / NS, s = blockIdx.x % NS;
    for (int i = threadIdx.x; i < (PSZ + 4) / 4; i += 256)
        ((int4*)h)[i] = make_int4(0, 0, 0, 0);
    __syncthreads();
    int lo = p * PSZ;
    int ebase = s * SSZ;
    const int4* d4 = (const int4*)(dst + ebase);
    const int4* s4 = (const int4*)(src + ebase);
    unsigned char* rk = rank + ebase;
    for (int i = threadIdx.x; i < SSZ / 4; i += 256) {
        int4 d = d4[i];
        int4 sv = s4[i];
        int t;
        t = d.x - lo;  if ((unsigned)t < PSZ) rk[4 * i + 0] = (unsigned char)(atomicAdd(&h[t], 1) & 0xffff);
        t = d.y - lo;  if ((unsigned)t < PSZ) rk[4 * i + 1] = (unsigned char)(atomicAdd(&h[t], 1) & 0xffff);
        t = d.z - lo;  if ((unsigned)t < PSZ) rk[4 * i + 2] = (unsigned char)(atomicAdd(&h[t], 1) & 0xffff);
        t = d.w - lo;  if ((unsigned)t < PSZ) rk[4 * i + 3] = (unsigned char)(atomicAdd(&h[t], 1) & 0xffff);
        t = sv.x - lo; if ((unsigned)t < PSZ) atomicAdd(&h[t], 0x10000);
        t = sv.y - lo; if ((unsigned)t < PSZ) atomicAdd(&h[t], 0x10000);
        t = sv.z - lo; if ((unsigned)t < PSZ) atomicAdd(&h[t], 0x10000);
        t = sv.w - lo; if ((unsigned)t < PSZ) atomicAdd(&h[t], 0x10000);
    }
    __syncthreads();
    unsigned char* ip = inpart + (size_t)s * N_NODES + lo;
    unsigned char* op = outpart + (size_t)s * N_NODES + lo;
    for (int i = threadIdx.x; i < PSZ / 2; i += 256) {
        int v0 = h[2 * i], v1 = h[2 * i + 1];
        uchar2 iv, ov;
        iv.x = (unsigned char)(v0 & 0xff);
        iv.y = (unsigned char)(v1 & 0xff);
        ov.x = (unsigned char)((v0 >> 16) & 0xff);
        ov.y = (unsigned char)((v1 >> 16) & 0xff);
        ((uchar2*)ip)[i] = iv;
        ((uchar2*)op)[i] = ov;
    }
}

// ---------------------------------------------------------------------------
// Fused: reduce u8 segment partials -> degrees AND rewrite inpart in place
// into the exclusive within-row segment prefix; features/norms (fp8 table);
// block scan; per-graph node counts.
// ---------------------------------------------------------------------------
__global__ void scan_block_feat_kernel(unsigned char* __restrict__ inpart,
                                       const unsigned char* __restrict__ outpart,
                                       const int* __restrict__ graph_ids,
                                       int* __restrict__ row_start, int* __restrict__ blk_sums,
                                       float* __restrict__ norm_src, float* __restrict__ norm_dst,
                                       uchar4* __restrict__ hs0, float* __restrict__ gcnt, int N) {
    __shared__ int ghist[64];
    if (threadIdx.x < 64) ghist[threadIdx.x] = 0;
    int i = blockIdx.x * 256 + threadIdx.x;
    int din_i = 0, dout_i = 0;
    if (i < N) {
        unsigned char run = 0;
#pragma unroll
        for (int s = 0; s < NS; ++s) {
            unsigned char c = inpart[(size_t)s * N_NODES + i];
            inpart[(size_t)s * N_NODES + i] = run;     // prefix rewrite in place
            run = (unsigned char)(run + c);
            dout_i += outpart[(size_t)s * N_NODES + i];
        }
        din_i = (int)run;
        float din = (float)din_i;
        float dout = (float)dout_i;
        float ns = 1.0f / sqrtf(fmaxf(dout, 1.0f));
        float nd = 1.0f / sqrtf(fmaxf(din, 1.0f));
        norm_src[i] = ns;
        norm_dst[i] = nd;
        float h1 = din;
        float h2 = (din - 3.0f > 0.0f) ? 1.0f : 0.0f;
        float h3 = 3.0f / din;
        float h4 = (din - 4.0f > 0.0f) ? 1.0f : 0.0f;
        uchar4 q;
        q.x = f_to_fp8(h1 * ns);
        q.y = f_to_fp8(h2 * ns);
        q.z = f_to_fp8(h3 * ns);
        q.w = f_to_fp8(h4 * ns);
        hs0[i] = q;
    }
    __syncthreads();
    if (i < N) atomicAdd(&ghist[graph_ids[i]], 1);
    int lane = threadIdx.x & 63;
    int wid = threadIdx.x >> 6;
    int x = din_i;
#pragma unroll
    for (int off = 1; off < 64; off <<= 1) {
        int t = __shfl_up(x, off);
        if (lane >= off) x += t;
    }
    __shared__ int wsum[4];
    if (lane == 63) wsum[wid] = x;
    __syncthreads();
    int woff = 0;
    for (int w = 0; w < wid; ++w) woff += wsum[w];
    int incl = x + woff;
    if (i < N) row_start[i] = incl - din_i;
    if (threadIdx.x == 255) blk_sums[blockIdx.x] = incl;
    if (threadIdx.x < 64 && ghist[threadIdx.x] > 0)
        atomicAdd(&gcnt[threadIdx.x], (float)ghist[threadIdx.x]);
}

// ---------------------------------------------------------------------------
// Slim: finalize row_start only (each block re-scans the 196 block sums).
// ---------------------------------------------------------------------------
__global__ void row_add_kernel(int* __restrict__ row_start,
                               const int* __restrict__ blk_sums, int N) {
    __shared__ int sOff[256];
    int t = threadIdx.x;
    int v = (t < NB) ? blk_sums[t] : 0;
    int lane = t & 63;
    int wid = t >> 6;
    int x = v;
#pragma unroll
    for (int off = 1; off < 64; off <<= 1) {
        int tt = __shfl_up(x, off);
        if (lane >= off) x += tt;
    }
    __shared__ int wsum[4];
    if (lane == 63) wsum[wid] = x;
    __syncthreads();
    int woff = 0;
    for (int w = 0; w < wid; ++w) woff += wsum[w];
    sOff[t] = x + woff - v;              // exclusive prefix of blk_sums
    __syncthreads();
    int i = blockIdx.x * 256 + threadIdx.x;
    if (blockIdx.x == 0 && threadIdx.x == 0) row_start[N] = N_EDGES;
    if (i < N) row_start[i] += sOff[blockIdx.x];
}

// ---------------------------------------------------------------------------
// Rank-based CSR fill: pos = row_start[d] + pref[s][d] + rank[e].
// csr_src is u16 (node ids < 50000 < 65536).
// ---------------------------------------------------------------------------
__global__ __launch_bounds__(256) void csr_fill_kernel(const int* __restrict__ src,
                                                       const int* __restrict__ dst,
                                                       const int* __restrict__ row_start,
                                                       const unsigned char* __restrict__ inpart,
                                                       const unsigned char* __restrict__ rank,
                                                       unsigned short* __restrict__ csr_src) {
    int i = blockIdx.x * 256 + threadIdx.x;          // edge-quad index
    if (i >= N_EDGES / 4) return;
    int4 d = ((const int4*)dst)[i];
    int4 sv = ((const int4*)src)[i];
    uchar4 rk = ((const uchar4*)rank)[i];
    int s = (4 * i) / SSZ;                           // uniform per SSZ/4 quads
    const unsigned char* pref = inpart + (size_t)s * N_NODES;
    csr_src[row_start[d.x] + (int)pref[d.x] + (int)rk.x] = (unsigned short)sv.x;
    csr_src[row_start[d.y] + (int)pref[d.y] + (int)rk.y] = (unsigned short)sv.y;
    csr_src[row_start[d.z] + (int)pref[d.z] + (int)rk.z] = (unsigned short)sv.z;
    csr_src[row_start[d.w] + (int)pref[d.w] + (int)rk.w] = (unsigned short)sv.w;
}

// ---------------------------------------------------------------------------
// Layer 1: IN=4 -> H=64. 16-lane-group structure (R7, proven).
// ---------------------------------------------------------------------------
__global__ __launch_bounds__(256) void conv4_kernel(const unsigned char* __restrict__ hs0,
                                                    const int* __restrict__ row_start,
                                                    const unsigned short* __restrict__ csr_src,
                                                    const float* __restrict__ norm_src,
                                                    const float* __restrict__ norm_dst,
                                                    const float* __restrict__ W,
                                                    const float* __restrict__ b,
                                                    unsigned char* __restrict__ out, int N) {
    __shared__ float sW[4 * 64];
    __shared__ float sb[64];
    sW[threadIdx.x] = W[threadIdx.x];
    if (threadIdx.x < 64) sb[threadIdx.x] = b[threadIdx.x];

    const int lane = threadIdx.x & 63;
    const int wavei = threadIdx.x >> 6;
    const int l16 = lane & 15;
    const int node = blockIdx.x * 16 + wavei * 4 + (lane >> 4);   // 3125*16 = N

    const int rs = row_start[node];                 // group-uniform
    const int deg = row_start[node + 1] - rs;
    const int ncg = (deg + 15) >> 4;

    float a0 = 0.f, a1 = 0.f, a2 = 0.f, a3 = 0.f;
    for (int c = 0; c < ncg; ++c) {                 // group-divergent, exec-masked
        int off = c * 16 + l16;
        unsigned pos = (unsigned)(rs + off);
        if (pos > (unsigned)(N_EDGES - 1)) pos = N_EDGES - 1;
        unsigned idx = csr_src[pos];
        unsigned tv = *(const unsigned*)(hs0 + ((size_t)idx << 2));
        if (off >= deg) tv = 0u;                    // fp8 0x00 == 0.0f
        a0 += fp8_to_f((unsigned char)(tv & 0xff));
        a1 += fp8_to_f((unsigned char)((tv >> 8) & 0xff));
        a2 += fp8_to_f((unsigned char)((tv >> 16) & 0xff));
        a3 += fp8_to_f((unsigned char)((tv >> 24) & 0xff));
    }
#pragma unroll
    for (int o = 1; o < 16; o <<= 1) {              // reduce within 16-lane group
        a0 += __shfl_xor(a0, o);
        a1 += __shfl_xor(a1, o);
        a2 += __shfl_xor(a2, o);
        a3 += __shfl_xor(a3, o);
    }
    __syncthreads();                                // sW/sb ready
    float nd = norm_dst[node];
    float ns = norm_src[node];
    uchar4 q;
    unsigned char* qp = (unsigned char*)&q;
#pragma unroll
    for (int j = 0; j < 4; ++j) {
        int f = l16 * 4 + j;
        float r = sb[f] + nd * (a0 * sW[f] + a1 * sW[64 + f] +
                                a2 * sW[128 + f] + a3 * sW[192 + f]);
        qp[j] = f_to_fp8(fmaxf(r, 0.0f) * ns);
    }
    *(uchar4*)(out + (size_t)node * 64 + l16 * 4) = q;
}

// ---------------------------------------------------------------------------
// Layers 2-4: H=64 -> H=64. R8: one node per EIGHT-lane group.
//  * 8 nodes/wave, 16 nodes/block (128 thr, 2 waves), grid 3125 exact.
//    (128-thr blocks: 16 wg/CU cap x 2 waves = 32 waves/CU — avoids R5's
//    64-thr occupancy trap.)
//  * Gather: 8 lanes x dwordx2 per row — ONE VMEM instr serves 8 rows
//    (512 B), halving gather instr count vs the 16-lane version (1/8
//    instr/edge); double-buffered tA/tB keeps 16 rows in flight.
//  * Per-node edge accumulation order unchanged => bit-identical numerics.
//  * MFMA: A-fragment (16 rows) shared; each wave does two 16-col slices.
// ---------------------------------------------------------------------------
#define GLOAD8(T, IDX)                                                     \
    _Pragma("unroll")                                                      \
    for (int j = 0; j < 8; ++j) {                                          \
        int si = __shfl(IDX, blane + j);                                   \
        T[j] = *(const uint2*)(hs_in + (((size_t)(unsigned)si) << 6)       \
                               + (l8 << 3));                               \
    }

#define ACCUM8(T, CB)                                                      \
    _Pragma("unroll")                                                      \
    for (int j = 0; j < 8; ++j) {                                          \
        float mk = ((CB) + j < deg) ? 1.0f : 0.0f;                         \
        unsigned lo_ = T[j].x, hi_ = T[j].y;                               \
        acc0 += mk * fp8_to_f((unsigned char)(lo_ & 0xff));                \
        acc1 += mk * fp8_to_f((unsigned char)((lo_ >> 8) & 0xff));         \
        acc2 += mk * fp8_to_f((unsigned char)((lo_ >> 16) & 0xff));        \
        acc3 += mk * fp8_to_f((unsigned char)((lo_ >> 24) & 0xff));        \
        acc4 += mk * fp8_to_f((unsigned char)(hi_ & 0xff));                \
        acc5 += mk * fp8_to_f((unsigned char)((hi_ >> 8) & 0xff));         \
        acc6 += mk * fp8_to_f((unsigned char)((hi_ >> 16) & 0xff));        \
        acc7 += mk * fp8_to_f((unsigned char)((hi_ >> 24) & 0xff));        \
    }

#define LOADI8(DST, C)                                                     \
    {                                                                      \
        unsigned p_ = (unsigned)(rs + (C) * 8 + l8);                       \
        if (p_ > (unsigned)(N_EDGES - 1)) p_ = N_EDGES - 1;                \
        DST = (int)csr_src[p_];                                            \
    }

__global__ __launch_bounds__(128) void conv64_kernel(
        const unsigned char* __restrict__ hs_in,
        const int* __restrict__ row_start,
        const unsigned short* __restrict__ csr_src,
        const float* __restrict__ norm_src,
        const float* __restrict__ norm_dst,
        const _Float16* __restrict__ WT, const float* __restrict__ b,
        unsigned char* __restrict__ out8,
        const int* __restrict__ graph_ids, float* __restrict__ gacc,
        int do_pool, int N) {
    __shared__ _Float16 sAgg[16][72];
    const int lane = threadIdx.x & 63;
    const int wavei = __builtin_amdgcn_readfirstlane(threadIdx.x >> 6);  // 0..1
    const int l8 = lane & 7;
    const int gsel = lane >> 3;                   // group 0..7
    const int blane = lane & 56;                  // group base lane
    const int vblock = blockIdx.x * 16;           // 50000 = 3125*16 exactly
    const int node = vblock + wavei * 8 + gsel;

    const int rs = row_start[node];               // group-uniform
    const int deg = row_start[node + 1] - rs;

    // wave-max chunk count (8 edges/chunk), max across the 8 groups
    int ncg = (deg + 7) >> 3;
    int m1 = max(ncg, __shfl_xor(ncg, 8));
    m1 = max(m1, __shfl_xor(m1, 16));
    int ncw = max(m1, __shfl_xor(m1, 32));

    float acc0 = 0.f, acc1 = 0.f, acc2 = 0.f, acc3 = 0.f;
    float acc4 = 0.f, acc5 = 0.f, acc6 = 0.f, acc7 = 0.f;

    uint2 tA[8], tB[8];
    int idx;
    if (ncw > 0) {
        LOADI8(idx, 0);
        GLOAD8(tA, idx);
        LOADI8(idx, 1);
        int k = 0;
        while (k + 2 <= ncw) {
            GLOAD8(tB, idx);                      // chunk k+1 in flight
            LOADI8(idx, k + 2);
            ACCUM8(tA, k * 8);
            if (k + 2 < ncw) {
                GLOAD8(tA, idx);                  // chunk k+2 in flight
                LOADI8(idx, k + 3);
            }
            ACCUM8(tB, (k + 1) * 8);
            k += 2;
        }
        if (k < ncw) { ACCUM8(tA, k * 8); }
    }

    // flush: scale by norm_dst, one 16 B LDS write per lane
    float nd = norm_dst[node];
    half8 fv;
    fv[0] = (_Float16)(acc0 * nd); fv[1] = (_Float16)(acc1 * nd);
    fv[2] = (_Float16)(acc2 * nd); fv[3] = (_Float16)(acc3 * nd);
    fv[4] = (_Float16)(acc4 * nd); fv[5] = (_Float16)(acc5 * nd);
    fv[6] = (_Float16)(acc6 * nd); fv[7] = (_Float16)(acc7 * nd);
    *(half8*)(&sAgg[wavei * 8 + gsel][l8 * 8]) = fv;
    __syncthreads();

    // MFMA: A = sAgg[16][64]; each wave does two 16-col slices (A shared)
    const int l15 = lane & 15;
    const int quad = lane >> 4;
    const _Float16* aRow = &sAgg[l15][quad * 8];
    half8 a0 = *(const half8*)(aRow);
    half8 a1 = *(const half8*)(aRow + 32);

#pragma unroll
    for (int t = 0; t < 2; ++t) {
        const int s = wavei * 2 + t;
        const int col = s * 16 + l15;
        const _Float16* bp = WT + ((size_t)col) * 64 + quad * 8;
        half8 b0 = *(const half8*)bp;
        half8 b1 = *(const half8*)(bp + 32);

        floatx4 cc = (floatx4){0.f, 0.f, 0.f, 0.f};
        cc = __builtin_amdgcn_mfma_f32_16x16x32_f16(a0, b0, cc, 0, 0, 0);
        cc = __builtin_amdgcn_mfma_f32_16x16x32_f16(a1, b1, cc, 0, 0, 0);

        float bias = b[col];
        if (do_pool) {
            int g0 = graph_ids[vblock];            // wave-uniform s_loads
            int g15 = graph_ids[vblock + 15];
            if (g0 == g15) {
                // fast path: all 16 nodes in one graph
                float fsum = 0.0f;
#pragma unroll
                for (int r = 0; r < 4; ++r)
                    fsum += fmaxf(cc[r] + bias, 0.0f);
                fsum += __shfl_xor(fsum, 16);      // combine 4 quads
                fsum += __shfl_xor(fsum, 32);
                if (quad == 0)
                    atomicAdd(&gacc[g0 * 64 + col], fsum);
            } else {
                // graph boundary (~1% of blocks): per-node atomics
#pragma unroll
                for (int r = 0; r < 4; ++r) {
                    int m = quad * 4 + r;
                    float val = fmaxf(cc[r] + bias, 0.0f);
                    atomicAdd(&gacc[graph_ids[vblock + m] * 64 + col], val);
                }
            }
        } else {
#pragma unroll
            for (int r = 0; r < 4; ++r) {
                int m = quad * 4 + r;
                int v = vblock + m;
                float val = fmaxf(cc[r] + bias, 0.0f) * norm_src[v];
                out8[(size_t)v * 64 + col] = f_to_fp8(val);
            }
        }
    }
}

// ---------------------------------------------------------------------------
// Pool stage 2: one wave per graph (16 blocks x 4 waves).
// ---------------------------------------------------------------------------
__global__ void pool2_kernel(const float* __restrict__ gacc, const float* __restrict__ gcnt,
                             const float* __restrict__ Wout, const float* __restrict__ bout,
                             float* __restrict__ out) {
    int lane = threadIdx.x & 63;
    int g = blockIdx.x * 4 + (threadIdx.x >> 6);   // 64 waves total
    float p = (gacc[g * 64 + lane] / gcnt[g]) * Wout[lane];
#pragma unroll
    for (int off = 32; off; off >>= 1) p += __shfl_xor(p, off);
    if (lane == 0) out[g] = 1.0f / (1.0f + expf(-(p + bout[0])));
}

// ---------------------------------------------------------------------------
extern "C" void kernel_launch(void* const* d_in, const int* in_sizes, int n_in,
                              void* d_out, int out_size, void* d_ws, size_t ws_size,
                              hipStream_t stream) {
    const int* src = (const int*)d_in[0];
    const int* dst = (const int*)d_in[1];
    const int* graph_ids = (const int*)d_in[2];
    const float* W1 = (const float*)d_in[3];
    const float* b1 = (const float*)d_in[4];
    const float* W2 = (const float*)d_in[5];
    const float* b2 = (const float*)d_in[6];
    const float* W3 = (const float*)d_in[7];
    const float* b3 = (const float*)d_in[8];
    const float* W4 = (const float*)d_in[9];
    const float* b4 = (const float*)d_in[10];
    const float* Wout = (const float*)d_in[11];
    const float* bout = (const float*)d_in[12];
    float* out = (float*)d_out;

    const int N = N_NODES, E = N_EDGES;

    unsigned char* buf8A = (unsigned char*)d_ws;           // N*64 fp8
    unsigned char* buf8B = buf8A + (size_t)N * 64;         // N*64 fp8
    _Float16* WT   = (_Float16*)(buf8B + (size_t)N * 64);  // 3*4096 f16
    float* gacc = (float*)(WT + 3 * 4096);                 // 64*64 f32
    float* gcnt = gacc + 64 * 64;                          // 64 f32
    unsigned char* hs0 = (unsigned char*)(gcnt + 64);      // N*4 fp8 (4B-aligned)
    float* norm_src = (float*)(hs0 + (size_t)N * 4);       // N
    float* norm_dst = norm_src + N;                        // N
    unsigned short* csr_src = (unsigned short*)(norm_dst + N);   // E u16
    int* row_start = (int*)(csr_src + E);                  // N+1
    int* blk_sums  = row_start + (N + 1);                  // NB
    unsigned char* inpart  = (unsigned char*)(blk_sums + NB + 1);    // NS*N u8
    unsigned char* outpart = inpart + (size_t)NS * N;                // NS*N u8
    unsigned char* rank    = outpart + (size_t)NS * N;               // E u8

    // hist (256) + WT transpose (48) + gacc/gcnt zero (1)
    hist_wt_kernel<<<NP * NS + 49, 256, 0, stream>>>(src, dst, inpart, outpart, rank,
                                                     W2, W3, W4, WT, gacc);
    scan_block_feat_kernel<<<NB, 256, 0, stream>>>(inpart, outpart, graph_ids,
                                                   row_start, blk_sums,
                                                   norm_src, norm_dst, (uchar4*)hs0, gcnt, N);
    row_add_kernel<<<NB, 256, 0, stream>>>(row_start, blk_sums, N);
    csr_fill_kernel<<<(E / 4 + 255) / 256, 256, 0, stream>>>(src, dst, row_start, inpart,
                                                             rank, csr_src);

    const int CB = N / 16;          // 16 nodes/block
    conv4_kernel<<<CB, 256, 0, stream>>>(hs0, row_start, csr_src,
                                         norm_src, norm_dst, W1, b1, buf8A, N);
    conv64_kernel<<<CB, 128, 0, stream>>>(buf8A, row_start, csr_src, norm_src, norm_dst,
                                          WT + 0 * 4096, b2, buf8B, graph_ids, gacc, 0, N);
    conv64_kernel<<<CB, 128, 0, stream>>>(buf8B, row_start, csr_src, norm_src, norm_dst,
                                          WT + 1 * 4096, b3, buf8A, graph_ids, gacc, 0, N);
    conv64_kernel<<<CB, 128, 0, stream>>>(buf8A, row_start, csr_src, norm_src, norm_dst,
                                          WT + 2 * 4096, b4, (unsigned char*)nullptr,
                                          graph_ids, gacc, 1, N);

    pool2_kernel<<<16, 256, 0, stream>>>(gacc, gcnt, Wout, bout, out);
}